// Round 1
// 718.245 us; speedup vs baseline: 1.1318x; 1.1318x over previous
//
#include <hip/hip_runtime.h>
#include <stdint.h>

#define N_ITEMS 30000
#define N_USERS 20000
#define N_NODES 50000
#define N_EDGES 512000
#define D0 768
#define D1 128
#define D2 64
#define OSTRIDE 960   // 768 + 128 + 64, d_out row stride

typedef short bf16x8 __attribute__((ext_vector_type(8)));
typedef float f32x4  __attribute__((ext_vector_type(4)));
typedef unsigned short u16x4 __attribute__((ext_vector_type(4)));
typedef unsigned short u16x2 __attribute__((ext_vector_type(2)));

__device__ __forceinline__ unsigned short f2bf(float x) {
    union { float f; uint32_t u; } v; v.f = x;
    uint32_t u = v.u;
    return (unsigned short)((u + 0x7FFF + ((u >> 16) & 1)) >> 16);  // RNE
}
__device__ __forceinline__ float bf2f(unsigned short s) {
    union { uint32_t u; float f; } v; v.u = ((uint32_t)s) << 16; return v.f;
}

// ---------------------------------------------------------------------------
// Kernel 1: ego0 = concat(item, user) -> d_out cols [0,768) fp32 (+bf16 mirror)
// ---------------------------------------------------------------------------
__global__ __launch_bounds__(256) void copy_ego0(const float* __restrict__ item,
                                                 const float* __restrict__ user,
                                                 float* __restrict__ out,
                                                 unsigned short* __restrict__ outb) {
    int idx = blockIdx.x * 256 + threadIdx.x;
    if (idx >= N_NODES * (D0 / 4)) return;
    int row = idx / (D0 / 4);
    int c4  = idx % (D0 / 4);
    const float4* src = (row < N_ITEMS)
        ? (const float4*)(item + (size_t)row * D0)
        : (const float4*)(user + (size_t)(row - N_ITEMS) * D0);
    float4 v = src[c4];
    *(float4*)(out + (size_t)row * OSTRIDE + c4 * 4) = v;
    if (outb) {
        u16x4 b;
        b[0] = f2bf(v.x); b[1] = f2bf(v.y); b[2] = f2bf(v.z); b[3] = f2bf(v.w);
        *(u16x4*)(outb + (size_t)row * D0 + c4 * 4) = b;
    }
}

// ---------------------------------------------------------------------------
// CSR build: histogram -> single-block scan -> fill
// ---------------------------------------------------------------------------
__global__ __launch_bounds__(256) void histogram_kernel(const int* __restrict__ rows,
                                                        int* __restrict__ counts) {
    int e = blockIdx.x * 256 + threadIdx.x;
    if (e < N_EDGES) atomicAdd(&counts[rows[e]], 1);
}

#define SCAN_THREADS 1024
__global__ __launch_bounds__(1024) void scan_kernel(const int* __restrict__ counts,
                                                    int* __restrict__ offsets,
                                                    int* __restrict__ cursors) {
    __shared__ int partials[SCAN_THREADS];
    const int CH = (N_NODES + SCAN_THREADS - 1) / SCAN_THREADS;  // 49
    int t = threadIdx.x;
    int base = t * CH;
    int sum = 0;
    for (int i = 0; i < CH; i++) {
        int idx = base + i;
        if (idx < N_NODES) sum += counts[idx];
    }
    partials[t] = sum;
    __syncthreads();
    for (int off = 1; off < SCAN_THREADS; off <<= 1) {
        int add = (t >= off) ? partials[t - off] : 0;
        __syncthreads();
        partials[t] += add;
        __syncthreads();
    }
    int run = (t == 0) ? 0 : partials[t - 1];
    for (int i = 0; i < CH; i++) {
        int idx = base + i;
        if (idx < N_NODES) {
            offsets[idx] = run;
            cursors[idx] = run;
            run += counts[idx];
        }
    }
    if (t == SCAN_THREADS - 1) offsets[N_NODES] = N_EDGES;
}

__global__ __launch_bounds__(256) void fill_kernel(const float* __restrict__ vals,
                                                   const int* __restrict__ rows,
                                                   const int* __restrict__ cols,
                                                   int* __restrict__ cursors,
                                                   float* __restrict__ svals,
                                                   int* __restrict__ scols) {
    int e = blockIdx.x * 256 + threadIdx.x;
    if (e >= N_EDGES) return;
    int pos = atomicAdd(&cursors[rows[e]], 1);
    svals[pos] = vals[e];
    scols[pos] = cols[e];
}

// ---------------------------------------------------------------------------
// Weight prep: W (K x N fp32, row-major) -> bf16 in MFMA B-frag order.
// Frag (kk, nt): 64 lanes x 8 bf16; lane l holds B[k=kk*32+(l>>4)*8+j][n=nt*16+(l&15)]
// ---------------------------------------------------------------------------
template <int K, int N>
__global__ __launch_bounds__(256) void prep_wb(const float* __restrict__ W,
                                               unsigned short* __restrict__ Wb) {
    constexpr int FR = (K / 32) * (N / 16);
    int tid = blockIdx.x * 256 + threadIdx.x;
    if (tid >= FR * 64) return;
    int frag = tid >> 6, lane = tid & 63;
    int kk = frag / (N / 16), nt = frag % (N / 16);
    int quad = lane >> 4, n = lane & 15;
    unsigned short tmp[8];
#pragma unroll
    for (int jj = 0; jj < 8; jj++) {
        int k = kk * 32 + quad * 8 + jj;
        tmp[jj] = f2bf(W[(size_t)k * N + nt * 16 + n]);
    }
#pragma unroll
    for (int jj = 0; jj < 8; jj++) Wb[(size_t)tid * 8 + jj] = tmp[jj];
}

// ---------------------------------------------------------------------------
// Fused layer (MFMA), v2:
//  - gather neighbor rows from bf16 mirror (BSRC) -> halves gather bytes
//  - scols/svals loaded coalesced per wave, __shfl-broadcast per edge
//  - wide gather loads: 768: 3x(8B bf16x4 / 16B float4); 128: 1x(4B / 8B)
//  - layer0 runs 512 threads (same 49.6KB LDS -> 3 blk/CU -> 24 waves/CU)
//  - epilogue optionally emits bf16 mirror of the layer output (for next layer)
// ---------------------------------------------------------------------------
template <int DIN, int DOUT, int THREADS, bool BSRC>
__global__ __launch_bounds__(THREADS) void fused_layer_mfma(
    const int*   __restrict__ offsets,
    const float* __restrict__ svals,
    const int*   __restrict__ scols,
    const float* __restrict__ ego, int ego_stride,          // fp32 (self row + fallback)
    const unsigned short* __restrict__ egob,                // bf16 mirror (BSRC)
    const unsigned short* __restrict__ Wb1,
    const unsigned short* __restrict__ Wb2,
    const float* __restrict__ b1, const float* __restrict__ b2,
    float* __restrict__ out, int out_stride,
    unsigned short* __restrict__ outb)                      // bf16 mirror out (or null)
{
    constexpr int NPB   = 16;
    constexpr int WAVES = THREADS / 64;
    constexpr int NPW   = NPB / WAVES;       // nodes per wave in gather
    constexpr int KK    = DIN / 32;
    constexpr int NT    = DOUT / 16;
    constexpr int NTW   = NT / WAVES;        // n-tiles per wave in GEMM
    constexpr int PAD   = 8;
    constexpr int CW    = (DIN >= 256) ? 4 : 2;   // cols per lane per chunk
    constexpr int NC    = DIN / (64 * CW);        // chunks

    __shared__ unsigned short s_sum [NPB][DIN + PAD];
    __shared__ unsigned short s_prod[NPB][DIN + PAD];

    const int t = threadIdx.x;
    const int w = t >> 6, l = t & 63;
    const int node_base = blockIdx.x * NPB;

    // ---- gather: wave w handles nodes w*NPW .. w*NPW+NPW-1 ----
    for (int nn = 0; nn < NPW; nn++) {
        int n   = w * NPW + nn;
        int row = node_base + n;
        int beg = offsets[row], end = offsets[row + 1];
        float acc[NC * CW];
#pragma unroll
        for (int c = 0; c < NC * CW; c++) acc[c] = 0.f;

        auto gather_one = [&](int gc, float v) {
            if constexpr (BSRC) {
                const unsigned short* sp = egob + (size_t)gc * DIN;
#pragma unroll
                for (int c = 0; c < NC; c++) {
                    if constexpr (CW == 4) {
                        u16x4 q = *(const u16x4*)(sp + c * 256 + l * 4);
#pragma unroll
                        for (int j = 0; j < 4; j++)
                            acc[c * 4 + j] = fmaf(v, bf2f(q[j]), acc[c * 4 + j]);
                    } else {
                        u16x2 q = *(const u16x2*)(sp + l * 2);
                        acc[0] = fmaf(v, bf2f(q[0]), acc[0]);
                        acc[1] = fmaf(v, bf2f(q[1]), acc[1]);
                    }
                }
            } else {
                const float* sp = ego + (size_t)gc * ego_stride;
#pragma unroll
                for (int c = 0; c < NC; c++) {
                    if constexpr (CW == 4) {
                        float4 q = *(const float4*)(sp + c * 256 + l * 4);
                        acc[c * 4 + 0] = fmaf(v, q.x, acc[c * 4 + 0]);
                        acc[c * 4 + 1] = fmaf(v, q.y, acc[c * 4 + 1]);
                        acc[c * 4 + 2] = fmaf(v, q.z, acc[c * 4 + 2]);
                        acc[c * 4 + 3] = fmaf(v, q.w, acc[c * 4 + 3]);
                    } else {
                        float2 q = *(const float2*)(sp + l * 2);
                        acc[0] = fmaf(v, q.x, acc[0]);
                        acc[1] = fmaf(v, q.y, acc[1]);
                    }
                }
            }
        };

        // coalesced edge-list load + shfl broadcast (no per-edge broadcast loads)
        for (int base = beg; base < end; base += 64) {
            int cnt = min(64, end - base);
            int   cl = 0;
            float vl = 0.f;
            if (l < cnt) { cl = scols[base + l]; vl = svals[base + l]; }
            int u = 0;
            for (; u + 1 < cnt; u += 2) {
                int   g0 = __shfl(cl, u),     g1 = __shfl(cl, u + 1);
                float v0 = __shfl(vl, u),     v1 = __shfl(vl, u + 1);
                gather_one(g0, v0);
                gather_one(g1, v1);
            }
            if (u < cnt) gather_one(__shfl(cl, u), __shfl(vl, u));
        }

        // self row (fp32) + write bf16 sum/prod tiles to LDS
#pragma unroll
        for (int c = 0; c < NC; c++) {
            if constexpr (CW == 4) {
                float4 e4 = *(const float4*)(ego + (size_t)row * ego_stride + c * 256 + l * 4);
                float eg[4] = {e4.x, e4.y, e4.z, e4.w};
                u16x4 s, p;
#pragma unroll
                for (int j = 0; j < 4; j++) {
                    float a = acc[c * 4 + j];
                    s[j] = f2bf(a + eg[j]);
                    p[j] = f2bf(a * eg[j]);
                }
                *(u16x4*)&s_sum [n][c * 256 + l * 4] = s;
                *(u16x4*)&s_prod[n][c * 256 + l * 4] = p;
            } else {
                float2 e2 = *(const float2*)(ego + (size_t)row * ego_stride + l * 2);
                u16x2 s, p;
                s[0] = f2bf(acc[0] + e2.x); p[0] = f2bf(acc[0] * e2.x);
                s[1] = f2bf(acc[1] + e2.y); p[1] = f2bf(acc[1] * e2.y);
                *(u16x2*)&s_sum [n][l * 2] = s;
                *(u16x2*)&s_prod[n][l * 2] = p;
            }
        }
    }
    __syncthreads();

    // ---- MFMA dual-GEMM ----
    const int m = l & 15, quad = l >> 4;
    f32x4 accc[NTW] = {};
    for (int kk = 0; kk < KK; kk++) {
        bf16x8 a_s = *(const bf16x8*)&s_sum [m][kk * 32 + quad * 8];
        bf16x8 a_p = *(const bf16x8*)&s_prod[m][kk * 32 + quad * 8];
#pragma unroll
        for (int i = 0; i < NTW; i++) {
            int nt = w * NTW + i;
            bf16x8 bf1 = *(const bf16x8*)(Wb1 + ((size_t)(kk * NT + nt) * 64 + l) * 8);
            bf16x8 bf2 = *(const bf16x8*)(Wb2 + ((size_t)(kk * NT + nt) * 64 + l) * 8);
            accc[i] = __builtin_amdgcn_mfma_f32_16x16x32_bf16(a_s, bf1, accc[i], 0, 0, 0);
            accc[i] = __builtin_amdgcn_mfma_f32_16x16x32_bf16(a_p, bf2, accc[i], 0, 0, 0);
        }
    }

    // ---- epilogue: C layout col=lane&15, row=quad*4+reg ----
#pragma unroll
    for (int i = 0; i < NTW; i++) {
        int nt = w * NTW + i;
        int j  = nt * 16 + m;
        float bb = b1[j] + b2[j];
#pragma unroll
        for (int r = 0; r < 4; r++) {
            int node  = node_base + quad * 4 + r;
            float val = accc[i][r] + bb;
            val = val > 0.f ? val : 0.01f * val;
            out[(size_t)node * out_stride + j] = val;
            if (outb) outb[(size_t)node * DOUT + j] = f2bf(val);
        }
    }
}

// ---------------------------------------------------------------------------
// In-place L2 normalize of d_out cols [768,896) and [896,960), one wave/row.
// ---------------------------------------------------------------------------
__global__ __launch_bounds__(64) void normalize_kernel(float* __restrict__ out) {
    int row  = blockIdx.x;
    int lane = threadIdx.x;
    float* p1 = out + (size_t)row * OSTRIDE + D0;  // 128 elems
    float* p2 = p1 + D1;                           // 64 elems

    float2 v = *(float2*)(p1 + lane * 2);
    float ss = v.x * v.x + v.y * v.y;
#pragma unroll
    for (int off = 32; off > 0; off >>= 1) ss += __shfl_xor(ss, off, 64);
    float inv1 = 1.0f / fmaxf(sqrtf(ss), 1e-12f);
    v.x *= inv1; v.y *= inv1;
    *(float2*)(p1 + lane * 2) = v;

    float wv = p2[lane];
    float ss2 = wv * wv;
#pragma unroll
    for (int off = 32; off > 0; off >>= 1) ss2 += __shfl_xor(ss2, off, 64);
    p2[lane] = wv / fmaxf(sqrtf(ss2), 1e-12f);
}

// ---------------------------------------------------------------------------
extern "C" void kernel_launch(void* const* d_in, const int* in_sizes, int n_in,
                              void* d_out, int out_size, void* d_ws, size_t ws_size,
                              hipStream_t stream) {
    const float* item  = (const float*)d_in[0];
    const float* user  = (const float*)d_in[1];
    const float* W1_0  = (const float*)d_in[2];
    const float* b1_0  = (const float*)d_in[3];
    const float* W2_0  = (const float*)d_in[4];
    const float* b2_0  = (const float*)d_in[5];
    const float* W1_1  = (const float*)d_in[6];
    const float* b1_1  = (const float*)d_in[7];
    const float* W2_1  = (const float*)d_in[8];
    const float* b2_1  = (const float*)d_in[9];
    const float* evals = (const float*)d_in[10];
    const int*   erows = (const int*)d_in[11];
    const int*   ecols = (const int*)d_in[12];
    float* out = (float*)d_out;

    // workspace layout (all 16B-aligned)
    int*   counts  = (int*)d_ws;                          // 50000
    int*   offsets = counts + N_NODES;                    // 50001
    int*   cursors = offsets + (N_NODES + 1);             // ends 150001 ints
    float* svals   = (float*)((int*)d_ws + 150004);       // byte 600016
    int*   scols   = (int*)(svals + N_EDGES);
    unsigned short* wb1_0 = (unsigned short*)(scols + N_EDGES);
    unsigned short* wb2_0 = wb1_0 + (size_t)D0 * D1;
    unsigned short* wb1_1 = wb2_0 + (size_t)D0 * D1;
    unsigned short* wb2_1 = wb1_1 + (size_t)D1 * D2;
    unsigned short* ego0b = wb2_1 + (size_t)D1 * D2;      // byte 5122000, 76.8 MB
    unsigned short* ego1b = ego0b + (size_t)N_NODES * D0; // 12.8 MB

    const size_t need = 5122000 + (size_t)N_NODES * D0 * 2 + (size_t)N_NODES * D1 * 2;
    const bool big = ws_size >= need;   // bf16 gather mirrors fit in workspace?

    // ego0 -> d_out cols [0,768) (+ bf16 mirror if it fits)
    copy_ego0<<<(N_NODES * (D0 / 4) + 255) / 256, 256, 0, stream>>>(
        item, user, out, big ? ego0b : nullptr);

    // CSR build
    hipMemsetAsync(counts, 0, (size_t)N_NODES * sizeof(int), stream);
    histogram_kernel<<<(N_EDGES + 255) / 256, 256, 0, stream>>>(erows, counts);
    scan_kernel<<<1, SCAN_THREADS, 0, stream>>>(counts, offsets, cursors);
    fill_kernel<<<(N_EDGES + 255) / 256, 256, 0, stream>>>(evals, erows, ecols,
                                                           cursors, svals, scols);

    // weight prep -> bf16 frag order
    {
        constexpr int FR0 = (D0 / 32) * (D1 / 16);  // 192 frags
        constexpr int FR1 = (D1 / 32) * (D2 / 16);  // 16 frags
        prep_wb<D0, D1><<<(FR0 * 64 + 255) / 256, 256, 0, stream>>>(W1_0, wb1_0);
        prep_wb<D0, D1><<<(FR0 * 64 + 255) / 256, 256, 0, stream>>>(W2_0, wb2_0);
        prep_wb<D1, D2><<<(FR1 * 64 + 255) / 256, 256, 0, stream>>>(W1_1, wb1_1);
        prep_wb<D1, D2><<<(FR1 * 64 + 255) / 256, 256, 0, stream>>>(W2_1, wb2_1);
    }

    if (big) {
        // layer 0 -> ego1 fp32 into d_out cols [768,896) + bf16 mirror
        fused_layer_mfma<D0, D1, 512, true><<<N_NODES / 16, 512, 0, stream>>>(
            offsets, svals, scols, out, OSTRIDE, ego0b,
            wb1_0, wb2_0, b1_0, b2_0, out + D0, OSTRIDE, ego1b);
        // layer 1 -> ego2 into d_out cols [896,960)
        fused_layer_mfma<D1, D2, 256, true><<<N_NODES / 16, 256, 0, stream>>>(
            offsets, svals, scols, out + D0, OSTRIDE, ego1b,
            wb1_1, wb2_1, b1_1, b2_1, out + D0 + D1, OSTRIDE, nullptr);
    } else {
        fused_layer_mfma<D0, D1, 512, false><<<N_NODES / 16, 512, 0, stream>>>(
            offsets, svals, scols, out, OSTRIDE, nullptr,
            wb1_0, wb2_0, b1_0, b2_0, out + D0, OSTRIDE, nullptr);
        fused_layer_mfma<D1, D2, 256, false><<<N_NODES / 16, 256, 0, stream>>>(
            offsets, svals, scols, out + D0, OSTRIDE, nullptr,
            wb1_1, wb2_1, b1_1, b2_1, out + D0 + D1, OSTRIDE, nullptr);
    }

    // in-place normalize of ego1/ego2 segments (after layer 1)
    normalize_kernel<<<N_NODES, 64, 0, stream>>>(out);
}

// Round 2
// 705.377 us; speedup vs baseline: 1.1525x; 1.0182x over previous
//
#include <hip/hip_runtime.h>
#include <stdint.h>

#define N_ITEMS 30000
#define N_USERS 20000
#define N_NODES 50000
#define N_EDGES 512000
#define D0 768
#define D1 128
#define D2 64
#define OSTRIDE 960   // 768 + 128 + 64, d_out row stride

typedef short bf16x8 __attribute__((ext_vector_type(8)));
typedef float f32x4  __attribute__((ext_vector_type(4)));
typedef unsigned short u16x8 __attribute__((ext_vector_type(8)));
typedef unsigned short u16x4 __attribute__((ext_vector_type(4)));
typedef unsigned short u16x2 __attribute__((ext_vector_type(2)));

__device__ __forceinline__ unsigned short f2bf(float x) {
    union { float f; uint32_t u; } v; v.f = x;
    uint32_t u = v.u;
    return (unsigned short)((u + 0x7FFF + ((u >> 16) & 1)) >> 16);  // RNE
}
__device__ __forceinline__ float bf2f(unsigned short s) {
    union { uint32_t u; float f; } v; v.u = ((uint32_t)s) << 16; return v.f;
}

// ---------------------------------------------------------------------------
// Kernel 1: ego0 = concat(item, user) -> d_out cols [0,768) fp32 (+bf16 mirror)
// ---------------------------------------------------------------------------
__global__ __launch_bounds__(256) void copy_ego0(const float* __restrict__ item,
                                                 const float* __restrict__ user,
                                                 float* __restrict__ out,
                                                 unsigned short* __restrict__ outb) {
    int idx = blockIdx.x * 256 + threadIdx.x;
    if (idx >= N_NODES * (D0 / 4)) return;
    int row = idx / (D0 / 4);
    int c4  = idx % (D0 / 4);
    const float4* src = (row < N_ITEMS)
        ? (const float4*)(item + (size_t)row * D0)
        : (const float4*)(user + (size_t)(row - N_ITEMS) * D0);
    float4 v = src[c4];
    *(float4*)(out + (size_t)row * OSTRIDE + c4 * 4) = v;
    if (outb) {
        u16x4 b;
        b[0] = f2bf(v.x); b[1] = f2bf(v.y); b[2] = f2bf(v.z); b[3] = f2bf(v.w);
        *(u16x4*)(outb + (size_t)row * D0 + c4 * 4) = b;
    }
}

// ---------------------------------------------------------------------------
// CSR build: histogram -> single-block scan -> fill
// ---------------------------------------------------------------------------
__global__ __launch_bounds__(256) void histogram_kernel(const int* __restrict__ rows,
                                                        int* __restrict__ counts) {
    int e = blockIdx.x * 256 + threadIdx.x;
    if (e < N_EDGES) atomicAdd(&counts[rows[e]], 1);
}

#define SCAN_THREADS 1024
__global__ __launch_bounds__(1024) void scan_kernel(const int* __restrict__ counts,
                                                    int* __restrict__ offsets,
                                                    int* __restrict__ cursors) {
    __shared__ int partials[SCAN_THREADS];
    const int CH = (N_NODES + SCAN_THREADS - 1) / SCAN_THREADS;  // 49
    int t = threadIdx.x;
    int base = t * CH;
    int sum = 0;
    for (int i = 0; i < CH; i++) {
        int idx = base + i;
        if (idx < N_NODES) sum += counts[idx];
    }
    partials[t] = sum;
    __syncthreads();
    for (int off = 1; off < SCAN_THREADS; off <<= 1) {
        int add = (t >= off) ? partials[t - off] : 0;
        __syncthreads();
        partials[t] += add;
        __syncthreads();
    }
    int run = (t == 0) ? 0 : partials[t - 1];
    for (int i = 0; i < CH; i++) {
        int idx = base + i;
        if (idx < N_NODES) {
            offsets[idx] = run;
            cursors[idx] = run;
            run += counts[idx];
        }
    }
    if (t == SCAN_THREADS - 1) offsets[N_NODES] = N_EDGES;
}

__global__ __launch_bounds__(256) void fill_kernel(const float* __restrict__ vals,
                                                   const int* __restrict__ rows,
                                                   const int* __restrict__ cols,
                                                   int* __restrict__ cursors,
                                                   float* __restrict__ svals,
                                                   int* __restrict__ scols) {
    int e = blockIdx.x * 256 + threadIdx.x;
    if (e >= N_EDGES) return;
    int pos = atomicAdd(&cursors[rows[e]], 1);
    svals[pos] = vals[e];
    scols[pos] = cols[e];
}

// ---------------------------------------------------------------------------
// Weight prep: W (K x N fp32, row-major) -> bf16 in MFMA B-frag order.
// ---------------------------------------------------------------------------
template <int K, int N>
__global__ __launch_bounds__(256) void prep_wb(const float* __restrict__ W,
                                               unsigned short* __restrict__ Wb) {
    constexpr int FR = (K / 32) * (N / 16);
    int tid = blockIdx.x * 256 + threadIdx.x;
    if (tid >= FR * 64) return;
    int frag = tid >> 6, lane = tid & 63;
    int kk = frag / (N / 16), nt = frag % (N / 16);
    int quad = lane >> 4, n = lane & 15;
    unsigned short tmp[8];
#pragma unroll
    for (int jj = 0; jj < 8; jj++) {
        int k = kk * 32 + quad * 8 + jj;
        tmp[jj] = f2bf(W[(size_t)k * N + nt * 16 + n]);
    }
#pragma unroll
    for (int jj = 0; jj < 8; jj++) Wb[(size_t)tid * 8 + jj] = tmp[jj];
}

// ---------------------------------------------------------------------------
// Fused layer (MFMA), v3:
//  - gather from bf16 mirror; per-lane layout for DIN=768: 8 elems @ l*8 (16B)
//    + 4 elems @ 512+l*4 (8B) -> 2 loads/edge instead of 3
//  - edge loop unrolled x4, ALL loads issued before any FMA (8 loads in flight)
//  - self row read from bf16 mirror too (kills 154MB fp32 stream + L2 pollution)
//  - __launch_bounds__(512,6): LDS caps at 3 blk/CU (24 waves) -> VGPR budget 85
// ---------------------------------------------------------------------------
template <int DIN, int DOUT, int THREADS, bool BSRC>
__global__ __launch_bounds__(THREADS, (THREADS == 512 ? 6 : 4)) void fused_layer_mfma(
    const int*   __restrict__ offsets,
    const float* __restrict__ svals,
    const int*   __restrict__ scols,
    const float* __restrict__ ego, int ego_stride,          // fp32 (fallback only)
    const unsigned short* __restrict__ egob,                // bf16 mirror (BSRC)
    const unsigned short* __restrict__ Wb1,
    const unsigned short* __restrict__ Wb2,
    const float* __restrict__ b1, const float* __restrict__ b2,
    float* __restrict__ out, int out_stride,
    unsigned short* __restrict__ outb)                      // bf16 mirror out (or null)
{
    constexpr int NPB   = 16;
    constexpr int WAVES = THREADS / 64;
    constexpr int NPW   = NPB / WAVES;       // nodes per wave in gather
    constexpr int KK    = DIN / 32;
    constexpr int NT    = DOUT / 16;
    constexpr int NTW   = NT / WAVES;        // n-tiles per wave in GEMM
    constexpr int PAD   = 8;

    __shared__ unsigned short s_sum [NPB][DIN + PAD];
    __shared__ unsigned short s_prod[NPB][DIN + PAD];

    const int t = threadIdx.x;
    const int w = t >> 6, l = t & 63;
    const int node_base = blockIdx.x * NPB;

    // ---- gather: wave w handles nodes w*NPW .. w*NPW+NPW-1 ----
    for (int nn = 0; nn < NPW; nn++) {
        int n   = w * NPW + nn;
        int row = node_base + n;
        int beg = offsets[row], end = offsets[row + 1];

        if constexpr (BSRC && DIN == 768) {
            // self row prefetch (bf16) -- overlaps with edge processing
            u16x8 eg0 = *(const u16x8*)(egob + (size_t)row * 768 + l * 8);
            u16x4 eg1 = *(const u16x4*)(egob + (size_t)row * 768 + 512 + l * 4);
            float acc0[8] = {0.f, 0.f, 0.f, 0.f, 0.f, 0.f, 0.f, 0.f};
            float acc1[4] = {0.f, 0.f, 0.f, 0.f};

            for (int base = beg; base < end; base += 64) {
                int cnt = min(64, end - base);
                int   cl = 0;
                float vl = 0.f;
                if (l < cnt) { cl = scols[base + l]; vl = svals[base + l]; }
                int u = 0;
                for (; u + 4 <= cnt; u += 4) {
                    const unsigned short* sp0 = egob + (size_t)__shfl(cl, u + 0) * 768;
                    const unsigned short* sp1 = egob + (size_t)__shfl(cl, u + 1) * 768;
                    const unsigned short* sp2 = egob + (size_t)__shfl(cl, u + 2) * 768;
                    const unsigned short* sp3 = egob + (size_t)__shfl(cl, u + 3) * 768;
                    float v0 = __shfl(vl, u + 0), v1 = __shfl(vl, u + 1);
                    float v2 = __shfl(vl, u + 2), v3 = __shfl(vl, u + 3);
                    // issue all 8 loads before any FMA
                    u16x8 a0 = *(const u16x8*)(sp0 + l * 8);
                    u16x8 a1 = *(const u16x8*)(sp1 + l * 8);
                    u16x8 a2 = *(const u16x8*)(sp2 + l * 8);
                    u16x8 a3 = *(const u16x8*)(sp3 + l * 8);
                    u16x4 c0 = *(const u16x4*)(sp0 + 512 + l * 4);
                    u16x4 c1 = *(const u16x4*)(sp1 + 512 + l * 4);
                    u16x4 c2 = *(const u16x4*)(sp2 + 512 + l * 4);
                    u16x4 c3 = *(const u16x4*)(sp3 + 512 + l * 4);
#pragma unroll
                    for (int j = 0; j < 8; j++) {
                        acc0[j] = fmaf(v0, bf2f(a0[j]), acc0[j]);
                        acc0[j] = fmaf(v1, bf2f(a1[j]), acc0[j]);
                        acc0[j] = fmaf(v2, bf2f(a2[j]), acc0[j]);
                        acc0[j] = fmaf(v3, bf2f(a3[j]), acc0[j]);
                    }
#pragma unroll
                    for (int j = 0; j < 4; j++) {
                        acc1[j] = fmaf(v0, bf2f(c0[j]), acc1[j]);
                        acc1[j] = fmaf(v1, bf2f(c1[j]), acc1[j]);
                        acc1[j] = fmaf(v2, bf2f(c2[j]), acc1[j]);
                        acc1[j] = fmaf(v3, bf2f(c3[j]), acc1[j]);
                    }
                }
                for (; u < cnt; u++) {
                    const unsigned short* sp = egob + (size_t)__shfl(cl, u) * 768;
                    float v0 = __shfl(vl, u);
                    u16x8 a0 = *(const u16x8*)(sp + l * 8);
                    u16x4 c0 = *(const u16x4*)(sp + 512 + l * 4);
#pragma unroll
                    for (int j = 0; j < 8; j++) acc0[j] = fmaf(v0, bf2f(a0[j]), acc0[j]);
#pragma unroll
                    for (int j = 0; j < 4; j++) acc1[j] = fmaf(v0, bf2f(c0[j]), acc1[j]);
                }
            }
            u16x8 s0, p0; u16x4 s1, p1;
#pragma unroll
            for (int j = 0; j < 8; j++) {
                float e = bf2f(eg0[j]);
                s0[j] = f2bf(acc0[j] + e);
                p0[j] = f2bf(acc0[j] * e);
            }
#pragma unroll
            for (int j = 0; j < 4; j++) {
                float e = bf2f(eg1[j]);
                s1[j] = f2bf(acc1[j] + e);
                p1[j] = f2bf(acc1[j] * e);
            }
            *(u16x8*)&s_sum [n][l * 8] = s0;
            *(u16x8*)&s_prod[n][l * 8] = p0;
            *(u16x4*)&s_sum [n][512 + l * 4] = s1;
            *(u16x4*)&s_prod[n][512 + l * 4] = p1;
        } else if constexpr (BSRC && DIN == 128) {
            u16x2 eg = *(const u16x2*)(egob + (size_t)row * 128 + l * 2);
            float acc[2] = {0.f, 0.f};
            for (int base = beg; base < end; base += 64) {
                int cnt = min(64, end - base);
                int   cl = 0;
                float vl = 0.f;
                if (l < cnt) { cl = scols[base + l]; vl = svals[base + l]; }
                int u = 0;
                for (; u + 4 <= cnt; u += 4) {
                    const unsigned short* sp0 = egob + (size_t)__shfl(cl, u + 0) * 128;
                    const unsigned short* sp1 = egob + (size_t)__shfl(cl, u + 1) * 128;
                    const unsigned short* sp2 = egob + (size_t)__shfl(cl, u + 2) * 128;
                    const unsigned short* sp3 = egob + (size_t)__shfl(cl, u + 3) * 128;
                    float v0 = __shfl(vl, u + 0), v1 = __shfl(vl, u + 1);
                    float v2 = __shfl(vl, u + 2), v3 = __shfl(vl, u + 3);
                    u16x2 a0 = *(const u16x2*)(sp0 + l * 2);
                    u16x2 a1 = *(const u16x2*)(sp1 + l * 2);
                    u16x2 a2 = *(const u16x2*)(sp2 + l * 2);
                    u16x2 a3 = *(const u16x2*)(sp3 + l * 2);
#pragma unroll
                    for (int j = 0; j < 2; j++) {
                        acc[j] = fmaf(v0, bf2f(a0[j]), acc[j]);
                        acc[j] = fmaf(v1, bf2f(a1[j]), acc[j]);
                        acc[j] = fmaf(v2, bf2f(a2[j]), acc[j]);
                        acc[j] = fmaf(v3, bf2f(a3[j]), acc[j]);
                    }
                }
                for (; u < cnt; u++) {
                    const unsigned short* sp = egob + (size_t)__shfl(cl, u) * 128;
                    float v0 = __shfl(vl, u);
                    u16x2 a0 = *(const u16x2*)(sp + l * 2);
                    acc[0] = fmaf(v0, bf2f(a0[0]), acc[0]);
                    acc[1] = fmaf(v0, bf2f(a0[1]), acc[1]);
                }
            }
            u16x2 s, p;
            float e0 = bf2f(eg[0]), e1 = bf2f(eg[1]);
            s[0] = f2bf(acc[0] + e0); p[0] = f2bf(acc[0] * e0);
            s[1] = f2bf(acc[1] + e1); p[1] = f2bf(acc[1] * e1);
            *(u16x2*)&s_sum [n][l * 2] = s;
            *(u16x2*)&s_prod[n][l * 2] = p;
        } else {
            // fp32 fallback (workspace too small for mirrors)
            constexpr int CW = (DIN >= 256) ? 4 : 2;
            constexpr int NC = DIN / (64 * CW);
            float acc[NC * CW], eg[NC * CW];
#pragma unroll
            for (int c = 0; c < NC * CW; c++) acc[c] = 0.f;
#pragma unroll
            for (int c = 0; c < NC; c++) {
#pragma unroll
                for (int j = 0; j < CW; j++)
                    eg[c * CW + j] = ego[(size_t)row * ego_stride + c * 64 * CW + l * CW + j];
            }
            for (int base = beg; base < end; base += 64) {
                int cnt = min(64, end - base);
                int   cl = 0;
                float vl = 0.f;
                if (l < cnt) { cl = scols[base + l]; vl = svals[base + l]; }
                for (int u = 0; u < cnt; u++) {
                    const float* sp = ego + (size_t)__shfl(cl, u) * ego_stride;
                    float v0 = __shfl(vl, u);
#pragma unroll
                    for (int c = 0; c < NC; c++) {
#pragma unroll
                        for (int j = 0; j < CW; j++)
                            acc[c * CW + j] = fmaf(v0, sp[c * 64 * CW + l * CW + j], acc[c * CW + j]);
                    }
                }
            }
#pragma unroll
            for (int c = 0; c < NC * CW; c++) {
                int col = (c / CW) * 64 * CW + l * CW + (c % CW);
                s_sum [n][col] = f2bf(acc[c] + eg[c]);
                s_prod[n][col] = f2bf(acc[c] * eg[c]);
            }
        }
    }
    __syncthreads();

    // ---- MFMA dual-GEMM ----
    const int m = l & 15, quad = l >> 4;
    f32x4 accc[NTW] = {};
    for (int kk = 0; kk < KK; kk++) {
        bf16x8 a_s = *(const bf16x8*)&s_sum [m][kk * 32 + quad * 8];
        bf16x8 a_p = *(const bf16x8*)&s_prod[m][kk * 32 + quad * 8];
#pragma unroll
        for (int i = 0; i < NTW; i++) {
            int nt = w * NTW + i;
            bf16x8 bf1 = *(const bf16x8*)(Wb1 + ((size_t)(kk * NT + nt) * 64 + l) * 8);
            bf16x8 bf2 = *(const bf16x8*)(Wb2 + ((size_t)(kk * NT + nt) * 64 + l) * 8);
            accc[i] = __builtin_amdgcn_mfma_f32_16x16x32_bf16(a_s, bf1, accc[i], 0, 0, 0);
            accc[i] = __builtin_amdgcn_mfma_f32_16x16x32_bf16(a_p, bf2, accc[i], 0, 0, 0);
        }
    }

    // ---- epilogue: C layout col=lane&15, row=quad*4+reg ----
#pragma unroll
    for (int i = 0; i < NTW; i++) {
        int nt = w * NTW + i;
        int j  = nt * 16 + m;
        float bb = b1[j] + b2[j];
#pragma unroll
        for (int r = 0; r < 4; r++) {
            int node  = node_base + quad * 4 + r;
            float val = accc[i][r] + bb;
            val = val > 0.f ? val : 0.01f * val;
            out[(size_t)node * out_stride + j] = val;
            if (outb) outb[(size_t)node * DOUT + j] = f2bf(val);
        }
    }
}

// ---------------------------------------------------------------------------
// In-place L2 normalize of d_out cols [768,896) and [896,960). 4 rows/block.
// ---------------------------------------------------------------------------
__global__ __launch_bounds__(256) void normalize_kernel(float* __restrict__ out) {
    int row  = blockIdx.x * 4 + (threadIdx.x >> 6);
    int lane = threadIdx.x & 63;
    float* p1 = out + (size_t)row * OSTRIDE + D0;  // 128 elems
    float* p2 = p1 + D1;                           // 64 elems

    float2 v = *(float2*)(p1 + lane * 2);
    float ss = v.x * v.x + v.y * v.y;
#pragma unroll
    for (int off = 32; off > 0; off >>= 1) ss += __shfl_xor(ss, off, 64);
    float inv1 = 1.0f / fmaxf(sqrtf(ss), 1e-12f);
    v.x *= inv1; v.y *= inv1;
    *(float2*)(p1 + lane * 2) = v;

    float wv = p2[lane];
    float ss2 = wv * wv;
#pragma unroll
    for (int off = 32; off > 0; off >>= 1) ss2 += __shfl_xor(ss2, off, 64);
    p2[lane] = wv / fmaxf(sqrtf(ss2), 1e-12f);
}

// ---------------------------------------------------------------------------
extern "C" void kernel_launch(void* const* d_in, const int* in_sizes, int n_in,
                              void* d_out, int out_size, void* d_ws, size_t ws_size,
                              hipStream_t stream) {
    const float* item  = (const float*)d_in[0];
    const float* user  = (const float*)d_in[1];
    const float* W1_0  = (const float*)d_in[2];
    const float* b1_0  = (const float*)d_in[3];
    const float* W2_0  = (const float*)d_in[4];
    const float* b2_0  = (const float*)d_in[5];
    const float* W1_1  = (const float*)d_in[6];
    const float* b1_1  = (const float*)d_in[7];
    const float* W2_1  = (const float*)d_in[8];
    const float* b2_1  = (const float*)d_in[9];
    const float* evals = (const float*)d_in[10];
    const int*   erows = (const int*)d_in[11];
    const int*   ecols = (const int*)d_in[12];
    float* out = (float*)d_out;

    // workspace layout (all 16B-aligned)
    int*   counts  = (int*)d_ws;                          // 50000
    int*   offsets = counts + N_NODES;                    // 50001
    int*   cursors = offsets + (N_NODES + 1);             // ends 150001 ints
    float* svals   = (float*)((int*)d_ws + 150004);       // byte 600016
    int*   scols   = (int*)(svals + N_EDGES);
    unsigned short* wb1_0 = (unsigned short*)(scols + N_EDGES);
    unsigned short* wb2_0 = wb1_0 + (size_t)D0 * D1;
    unsigned short* wb1_1 = wb2_0 + (size_t)D0 * D1;
    unsigned short* wb2_1 = wb1_1 + (size_t)D1 * D2;
    unsigned short* ego0b = wb2_1 + (size_t)D1 * D2;      // byte 5122000, 76.8 MB
    unsigned short* ego1b = ego0b + (size_t)N_NODES * D0; // 12.8 MB

    const size_t need = 5122000 + (size_t)N_NODES * D0 * 2 + (size_t)N_NODES * D1 * 2;
    const bool big = ws_size >= need;   // bf16 gather mirrors fit in workspace?

    // ego0 -> d_out cols [0,768) (+ bf16 mirror if it fits)
    copy_ego0<<<(N_NODES * (D0 / 4) + 255) / 256, 256, 0, stream>>>(
        item, user, out, big ? ego0b : nullptr);

    // CSR build
    hipMemsetAsync(counts, 0, (size_t)N_NODES * sizeof(int), stream);
    histogram_kernel<<<(N_EDGES + 255) / 256, 256, 0, stream>>>(erows, counts);
    scan_kernel<<<1, SCAN_THREADS, 0, stream>>>(counts, offsets, cursors);
    fill_kernel<<<(N_EDGES + 255) / 256, 256, 0, stream>>>(evals, erows, ecols,
                                                           cursors, svals, scols);

    // weight prep -> bf16 frag order
    {
        constexpr int FR0 = (D0 / 32) * (D1 / 16);  // 192 frags
        constexpr int FR1 = (D1 / 32) * (D2 / 16);  // 16 frags
        prep_wb<D0, D1><<<(FR0 * 64 + 255) / 256, 256, 0, stream>>>(W1_0, wb1_0);
        prep_wb<D0, D1><<<(FR0 * 64 + 255) / 256, 256, 0, stream>>>(W2_0, wb2_0);
        prep_wb<D1, D2><<<(FR1 * 64 + 255) / 256, 256, 0, stream>>>(W1_1, wb1_1);
        prep_wb<D1, D2><<<(FR1 * 64 + 255) / 256, 256, 0, stream>>>(W2_1, wb2_1);
    }

    if (big) {
        // layer 0 -> ego1 fp32 into d_out cols [768,896) + bf16 mirror
        fused_layer_mfma<D0, D1, 512, true><<<N_NODES / 16, 512, 0, stream>>>(
            offsets, svals, scols, out, OSTRIDE, ego0b,
            wb1_0, wb2_0, b1_0, b2_0, out + D0, OSTRIDE, ego1b);
        // layer 1 -> ego2 into d_out cols [896,960)
        fused_layer_mfma<D1, D2, 256, true><<<N_NODES / 16, 256, 0, stream>>>(
            offsets, svals, scols, out + D0, OSTRIDE, ego1b,
            wb1_1, wb2_1, b1_1, b2_1, out + D0 + D1, OSTRIDE, nullptr);
    } else {
        fused_layer_mfma<D0, D1, 512, false><<<N_NODES / 16, 512, 0, stream>>>(
            offsets, svals, scols, out, OSTRIDE, nullptr,
            wb1_0, wb2_0, b1_0, b2_0, out + D0, OSTRIDE, nullptr);
        fused_layer_mfma<D1, D2, 256, false><<<N_NODES / 16, 256, 0, stream>>>(
            offsets, svals, scols, out + D0, OSTRIDE, nullptr,
            wb1_1, wb2_1, b1_1, b2_1, out + D0 + D1, OSTRIDE, nullptr);
    }

    // in-place normalize of ego1/ego2 segments (after layer 1)
    normalize_kernel<<<N_NODES / 4, 256, 0, stream>>>(out);
}

// Round 3
// 686.257 us; speedup vs baseline: 1.1846x; 1.0279x over previous
//
#include <hip/hip_runtime.h>
#include <stdint.h>

#define N_ITEMS 30000
#define N_USERS 20000
#define N_NODES 50000
#define N_EDGES 512000
#define D0 768
#define D1 128
#define D2 64
#define OSTRIDE 960   // 768 + 128 + 64, d_out row stride

typedef short bf16x8 __attribute__((ext_vector_type(8)));
typedef float f32x4  __attribute__((ext_vector_type(4)));
typedef unsigned short u16x8 __attribute__((ext_vector_type(8)));
typedef unsigned short u16x4 __attribute__((ext_vector_type(4)));
typedef unsigned short u16x2 __attribute__((ext_vector_type(2)));

__device__ __forceinline__ unsigned short f2bf(float x) {
    union { float f; uint32_t u; } v; v.f = x;
    uint32_t u = v.u;
    return (unsigned short)((u + 0x7FFF + ((u >> 16) & 1)) >> 16);  // RNE
}
__device__ __forceinline__ float bf2f(unsigned short s) {
    union { uint32_t u; float f; } v; v.u = ((uint32_t)s) << 16; return v.f;
}

// ---------------------------------------------------------------------------
// Kernel 1: ego0 = concat(item, user) -> d_out cols [0,768) fp32 (+bf16 mirror)
// Also zeroes the CSR counts array (replaces hipMemsetAsync dispatch).
// ---------------------------------------------------------------------------
__global__ __launch_bounds__(256) void copy_ego0(const float* __restrict__ item,
                                                 const float* __restrict__ user,
                                                 float* __restrict__ out,
                                                 unsigned short* __restrict__ outb,
                                                 int* __restrict__ counts) {
    int idx = blockIdx.x * 256 + threadIdx.x;
    if (idx < N_NODES) counts[idx] = 0;
    if (idx >= N_NODES * (D0 / 4)) return;
    int row = idx / (D0 / 4);
    int c4  = idx % (D0 / 4);
    const float4* src = (row < N_ITEMS)
        ? (const float4*)(item + (size_t)row * D0)
        : (const float4*)(user + (size_t)(row - N_ITEMS) * D0);
    float4 v = src[c4];
    *(float4*)(out + (size_t)row * OSTRIDE + c4 * 4) = v;
    if (outb) {
        u16x4 b;
        b[0] = f2bf(v.x); b[1] = f2bf(v.y); b[2] = f2bf(v.z); b[3] = f2bf(v.w);
        *(u16x4*)(outb + (size_t)row * D0 + c4 * 4) = b;
    }
}

// ---------------------------------------------------------------------------
// Weight prep body: W (K x N fp32, row-major) -> bf16 in MFMA B-frag order.
// ---------------------------------------------------------------------------
template <int K, int N>
__device__ __forceinline__ void prep_body(const float* __restrict__ W,
                                          unsigned short* __restrict__ Wb, int tid) {
    constexpr int FR = (K / 32) * (N / 16);
    if (tid >= FR * 64) return;
    int frag = tid >> 6, lane = tid & 63;
    int kk = frag / (N / 16), nt = frag % (N / 16);
    int quad = lane >> 4, n = lane & 15;
    unsigned short tmp[8];
#pragma unroll
    for (int jj = 0; jj < 8; jj++) {
        int k = kk * 32 + quad * 8 + jj;
        tmp[jj] = f2bf(W[(size_t)k * N + nt * 16 + n]);
    }
#pragma unroll
    for (int jj = 0; jj < 8; jj++) Wb[(size_t)tid * 8 + jj] = tmp[jj];
}

// ---------------------------------------------------------------------------
// aux_kernel: histogram (blocks 0..1999) + 4 weight preps (blocks 2000..2103)
// ---------------------------------------------------------------------------
__global__ __launch_bounds__(256) void aux_kernel(
    const int* __restrict__ erows, int* __restrict__ counts,
    const float* __restrict__ W1_0, const float* __restrict__ W2_0,
    const float* __restrict__ W1_1, const float* __restrict__ W2_1,
    unsigned short* __restrict__ wb1_0, unsigned short* __restrict__ wb2_0,
    unsigned short* __restrict__ wb1_1, unsigned short* __restrict__ wb2_1) {
    int b = blockIdx.x, t = threadIdx.x;
    if (b < 2000) {                       // histogram: 2000*256 == N_EDGES
        int e = b * 256 + t;
        atomicAdd(&counts[erows[e]], 1);
    } else if (b < 2048) {
        prep_body<D0, D1>(W1_0, wb1_0, (b - 2000) * 256 + t);
    } else if (b < 2096) {
        prep_body<D0, D1>(W2_0, wb2_0, (b - 2048) * 256 + t);
    } else if (b < 2100) {
        prep_body<D1, D2>(W1_1, wb1_1, (b - 2096) * 256 + t);
    } else {
        prep_body<D1, D2>(W2_1, wb2_1, (b - 2100) * 256 + t);
    }
}

#define SCAN_THREADS 1024
__global__ __launch_bounds__(1024) void scan_kernel(const int* __restrict__ counts,
                                                    int* __restrict__ offsets,
                                                    int* __restrict__ cursors) {
    __shared__ int partials[SCAN_THREADS];
    const int CH = (N_NODES + SCAN_THREADS - 1) / SCAN_THREADS;  // 49
    int t = threadIdx.x;
    int base = t * CH;
    int sum = 0;
    for (int i = 0; i < CH; i++) {
        int idx = base + i;
        if (idx < N_NODES) sum += counts[idx];
    }
    partials[t] = sum;
    __syncthreads();
    for (int off = 1; off < SCAN_THREADS; off <<= 1) {
        int add = (t >= off) ? partials[t - off] : 0;
        __syncthreads();
        partials[t] += add;
        __syncthreads();
    }
    int run = (t == 0) ? 0 : partials[t - 1];
    for (int i = 0; i < CH; i++) {
        int idx = base + i;
        if (idx < N_NODES) {
            offsets[idx] = run;
            cursors[idx] = run;
            run += counts[idx];
        }
    }
    if (t == SCAN_THREADS - 1) offsets[N_NODES] = N_EDGES;
}

__global__ __launch_bounds__(256) void fill_kernel(const float* __restrict__ vals,
                                                   const int* __restrict__ rows,
                                                   const int* __restrict__ cols,
                                                   int* __restrict__ cursors,
                                                   float* __restrict__ svals,
                                                   int* __restrict__ scols) {
    int e = blockIdx.x * 256 + threadIdx.x;
    if (e >= N_EDGES) return;
    int pos = atomicAdd(&cursors[rows[e]], 1);
    svals[pos] = vals[e];
    scols[pos] = cols[e];
}

// ---------------------------------------------------------------------------
// Fused layer (MFMA) v4:
//  - gather from bf16 mirror, 2 wide loads/edge, x4 unroll (at its measured
//    TCC-miss service ceiling ~46 G lines/s -- do not touch)
//  - FUSE_NORM (layer 1): epilogue normalizes ego2 (from fp32 acc via LDS)
//    and ego1 fp32 rows of this block -> kills normalize_kernel dispatch
// ---------------------------------------------------------------------------
template <int DIN, int DOUT, int THREADS, bool BSRC, bool FUSE_NORM>
__global__ __launch_bounds__(THREADS, (THREADS == 512 ? 6 : 4)) void fused_layer_mfma(
    const int*   __restrict__ offsets,
    const float* __restrict__ svals,
    const int*   __restrict__ scols,
    const float* __restrict__ ego, int ego_stride,          // fp32 (fallback only)
    const unsigned short* __restrict__ egob,                // bf16 mirror (BSRC)
    const unsigned short* __restrict__ Wb1,
    const unsigned short* __restrict__ Wb2,
    const float* __restrict__ b1, const float* __restrict__ b2,
    float* __restrict__ out, int out_stride,
    unsigned short* __restrict__ outb,                      // bf16 mirror out (or null)
    float* __restrict__ ego1_f32)                           // FUSE_NORM: fp32 ego1 base
{
    constexpr int NPB   = 16;
    constexpr int WAVES = THREADS / 64;
    constexpr int NPW   = NPB / WAVES;       // nodes per wave in gather
    constexpr int KK    = DIN / 32;
    constexpr int NT    = DOUT / 16;
    constexpr int NTW   = NT / WAVES;        // n-tiles per wave in GEMM
    constexpr int PAD   = 8;

    __shared__ unsigned short s_sum [NPB][DIN + PAD];
    __shared__ unsigned short s_prod[NPB][DIN + PAD];
    __shared__ float s_o2[FUSE_NORM ? NPB : 1][FUSE_NORM ? (DOUT + 4) : 1];

    const int t = threadIdx.x;
    const int w = t >> 6, l = t & 63;
    const int node_base = blockIdx.x * NPB;

    // ---- gather: wave w handles nodes w*NPW .. w*NPW+NPW-1 ----
    for (int nn = 0; nn < NPW; nn++) {
        int n   = w * NPW + nn;
        int row = node_base + n;
        int beg = offsets[row], end = offsets[row + 1];

        if constexpr (BSRC && DIN == 768) {
            u16x8 eg0 = *(const u16x8*)(egob + (size_t)row * 768 + l * 8);
            u16x4 eg1 = *(const u16x4*)(egob + (size_t)row * 768 + 512 + l * 4);
            float acc0[8] = {0.f, 0.f, 0.f, 0.f, 0.f, 0.f, 0.f, 0.f};
            float acc1[4] = {0.f, 0.f, 0.f, 0.f};

            for (int base = beg; base < end; base += 64) {
                int cnt = min(64, end - base);
                int   cl = 0;
                float vl = 0.f;
                if (l < cnt) { cl = scols[base + l]; vl = svals[base + l]; }
                int u = 0;
                for (; u + 4 <= cnt; u += 4) {
                    const unsigned short* sp0 = egob + (size_t)__shfl(cl, u + 0) * 768;
                    const unsigned short* sp1 = egob + (size_t)__shfl(cl, u + 1) * 768;
                    const unsigned short* sp2 = egob + (size_t)__shfl(cl, u + 2) * 768;
                    const unsigned short* sp3 = egob + (size_t)__shfl(cl, u + 3) * 768;
                    float v0 = __shfl(vl, u + 0), v1 = __shfl(vl, u + 1);
                    float v2 = __shfl(vl, u + 2), v3 = __shfl(vl, u + 3);
                    u16x8 a0 = *(const u16x8*)(sp0 + l * 8);
                    u16x8 a1 = *(const u16x8*)(sp1 + l * 8);
                    u16x8 a2 = *(const u16x8*)(sp2 + l * 8);
                    u16x8 a3 = *(const u16x8*)(sp3 + l * 8);
                    u16x4 c0 = *(const u16x4*)(sp0 + 512 + l * 4);
                    u16x4 c1 = *(const u16x4*)(sp1 + 512 + l * 4);
                    u16x4 c2 = *(const u16x4*)(sp2 + 512 + l * 4);
                    u16x4 c3 = *(const u16x4*)(sp3 + 512 + l * 4);
#pragma unroll
                    for (int j = 0; j < 8; j++) {
                        acc0[j] = fmaf(v0, bf2f(a0[j]), acc0[j]);
                        acc0[j] = fmaf(v1, bf2f(a1[j]), acc0[j]);
                        acc0[j] = fmaf(v2, bf2f(a2[j]), acc0[j]);
                        acc0[j] = fmaf(v3, bf2f(a3[j]), acc0[j]);
                    }
#pragma unroll
                    for (int j = 0; j < 4; j++) {
                        acc1[j] = fmaf(v0, bf2f(c0[j]), acc1[j]);
                        acc1[j] = fmaf(v1, bf2f(c1[j]), acc1[j]);
                        acc1[j] = fmaf(v2, bf2f(c2[j]), acc1[j]);
                        acc1[j] = fmaf(v3, bf2f(c3[j]), acc1[j]);
                    }
                }
                for (; u < cnt; u++) {
                    const unsigned short* sp = egob + (size_t)__shfl(cl, u) * 768;
                    float v0 = __shfl(vl, u);
                    u16x8 a0 = *(const u16x8*)(sp + l * 8);
                    u16x4 c0 = *(const u16x4*)(sp + 512 + l * 4);
#pragma unroll
                    for (int j = 0; j < 8; j++) acc0[j] = fmaf(v0, bf2f(a0[j]), acc0[j]);
#pragma unroll
                    for (int j = 0; j < 4; j++) acc1[j] = fmaf(v0, bf2f(c0[j]), acc1[j]);
                }
            }
            u16x8 s0, p0; u16x4 s1, p1;
#pragma unroll
            for (int j = 0; j < 8; j++) {
                float e = bf2f(eg0[j]);
                s0[j] = f2bf(acc0[j] + e);
                p0[j] = f2bf(acc0[j] * e);
            }
#pragma unroll
            for (int j = 0; j < 4; j++) {
                float e = bf2f(eg1[j]);
                s1[j] = f2bf(acc1[j] + e);
                p1[j] = f2bf(acc1[j] * e);
            }
            *(u16x8*)&s_sum [n][l * 8] = s0;
            *(u16x8*)&s_prod[n][l * 8] = p0;
            *(u16x4*)&s_sum [n][512 + l * 4] = s1;
            *(u16x4*)&s_prod[n][512 + l * 4] = p1;
        } else if constexpr (BSRC && DIN == 128) {
            u16x2 eg = *(const u16x2*)(egob + (size_t)row * 128 + l * 2);
            float acc[2] = {0.f, 0.f};
            for (int base = beg; base < end; base += 64) {
                int cnt = min(64, end - base);
                int   cl = 0;
                float vl = 0.f;
                if (l < cnt) { cl = scols[base + l]; vl = svals[base + l]; }
                int u = 0;
                for (; u + 4 <= cnt; u += 4) {
                    const unsigned short* sp0 = egob + (size_t)__shfl(cl, u + 0) * 128;
                    const unsigned short* sp1 = egob + (size_t)__shfl(cl, u + 1) * 128;
                    const unsigned short* sp2 = egob + (size_t)__shfl(cl, u + 2) * 128;
                    const unsigned short* sp3 = egob + (size_t)__shfl(cl, u + 3) * 128;
                    float v0 = __shfl(vl, u + 0), v1 = __shfl(vl, u + 1);
                    float v2 = __shfl(vl, u + 2), v3 = __shfl(vl, u + 3);
                    u16x2 a0 = *(const u16x2*)(sp0 + l * 2);
                    u16x2 a1 = *(const u16x2*)(sp1 + l * 2);
                    u16x2 a2 = *(const u16x2*)(sp2 + l * 2);
                    u16x2 a3 = *(const u16x2*)(sp3 + l * 2);
#pragma unroll
                    for (int j = 0; j < 2; j++) {
                        acc[j] = fmaf(v0, bf2f(a0[j]), acc[j]);
                        acc[j] = fmaf(v1, bf2f(a1[j]), acc[j]);
                        acc[j] = fmaf(v2, bf2f(a2[j]), acc[j]);
                        acc[j] = fmaf(v3, bf2f(a3[j]), acc[j]);
                    }
                }
                for (; u < cnt; u++) {
                    const unsigned short* sp = egob + (size_t)__shfl(cl, u) * 128;
                    float v0 = __shfl(vl, u);
                    u16x2 a0 = *(const u16x2*)(sp + l * 2);
                    acc[0] = fmaf(v0, bf2f(a0[0]), acc[0]);
                    acc[1] = fmaf(v0, bf2f(a0[1]), acc[1]);
                }
            }
            u16x2 s, p;
            float e0 = bf2f(eg[0]), e1 = bf2f(eg[1]);
            s[0] = f2bf(acc[0] + e0); p[0] = f2bf(acc[0] * e0);
            s[1] = f2bf(acc[1] + e1); p[1] = f2bf(acc[1] * e1);
            *(u16x2*)&s_sum [n][l * 2] = s;
            *(u16x2*)&s_prod[n][l * 2] = p;
        } else {
            // fp32 fallback (workspace too small for mirrors)
            constexpr int CW = (DIN >= 256) ? 4 : 2;
            constexpr int NC = DIN / (64 * CW);
            float acc[NC * CW], eg[NC * CW];
#pragma unroll
            for (int c = 0; c < NC * CW; c++) acc[c] = 0.f;
#pragma unroll
            for (int c = 0; c < NC; c++) {
#pragma unroll
                for (int j = 0; j < CW; j++)
                    eg[c * CW + j] = ego[(size_t)row * ego_stride + c * 64 * CW + l * CW + j];
            }
            for (int base = beg; base < end; base += 64) {
                int cnt = min(64, end - base);
                int   cl = 0;
                float vl = 0.f;
                if (l < cnt) { cl = scols[base + l]; vl = svals[base + l]; }
                for (int u = 0; u < cnt; u++) {
                    const float* sp = ego + (size_t)__shfl(cl, u) * ego_stride;
                    float v0 = __shfl(vl, u);
#pragma unroll
                    for (int c = 0; c < NC; c++) {
#pragma unroll
                        for (int j = 0; j < CW; j++)
                            acc[c * CW + j] = fmaf(v0, sp[c * 64 * CW + l * CW + j], acc[c * CW + j]);
                    }
                }
            }
#pragma unroll
            for (int c = 0; c < NC * CW; c++) {
                int col = (c / CW) * 64 * CW + l * CW + (c % CW);
                s_sum [n][col] = f2bf(acc[c] + eg[c]);
                s_prod[n][col] = f2bf(acc[c] * eg[c]);
            }
        }
    }
    __syncthreads();

    // ---- MFMA dual-GEMM ----
    const int m = l & 15, quad = l >> 4;
    f32x4 accc[NTW] = {};
    for (int kk = 0; kk < KK; kk++) {
        bf16x8 a_s = *(const bf16x8*)&s_sum [m][kk * 32 + quad * 8];
        bf16x8 a_p = *(const bf16x8*)&s_prod[m][kk * 32 + quad * 8];
#pragma unroll
        for (int i = 0; i < NTW; i++) {
            int nt = w * NTW + i;
            bf16x8 bf1 = *(const bf16x8*)(Wb1 + ((size_t)(kk * NT + nt) * 64 + l) * 8);
            bf16x8 bf2 = *(const bf16x8*)(Wb2 + ((size_t)(kk * NT + nt) * 64 + l) * 8);
            accc[i] = __builtin_amdgcn_mfma_f32_16x16x32_bf16(a_s, bf1, accc[i], 0, 0, 0);
            accc[i] = __builtin_amdgcn_mfma_f32_16x16x32_bf16(a_p, bf2, accc[i], 0, 0, 0);
        }
    }

    // ---- epilogue: C layout col=lane&15, row=quad*4+reg ----
#pragma unroll
    for (int i = 0; i < NTW; i++) {
        int nt = w * NTW + i;
        int j  = nt * 16 + m;
        float bb = b1[j] + b2[j];
#pragma unroll
        for (int r = 0; r < 4; r++) {
            int node  = node_base + quad * 4 + r;
            float val = accc[i][r] + bb;
            val = val > 0.f ? val : 0.01f * val;
            if constexpr (FUSE_NORM) {
                s_o2[quad * 4 + r][j] = val;     // stage for in-block normalize
            } else {
                out[(size_t)node * out_stride + j] = val;
                if (outb) outb[(size_t)node * DOUT + j] = f2bf(val);
            }
        }
    }

    if constexpr (FUSE_NORM) {
        __syncthreads();
        // wave w normalizes nodes w*NPW2 .. ; 4 waves x 4 nodes (DOUT=64 path)
        static_assert(!FUSE_NORM || (DOUT == 64 && WAVES == 4), "fuse-norm layout");
#pragma unroll
        for (int nn = 0; nn < 4; nn++) {
            int nl  = w * 4 + nn;
            int row = node_base + nl;
            // ego2: lane l covers col l (64 cols)
            float v2 = s_o2[nl][l];
            float ss2 = v2 * v2;
#pragma unroll
            for (int off = 32; off > 0; off >>= 1) ss2 += __shfl_xor(ss2, off, 64);
            out[(size_t)row * out_stride + l] = v2 / fmaxf(sqrtf(ss2), 1e-12f);
            // ego1 fp32: 2 floats/lane (128 cols)
            float* p1 = ego1_f32 + (size_t)row * out_stride;
            float2 v1 = *(float2*)(p1 + l * 2);
            float ss1 = v1.x * v1.x + v1.y * v1.y;
#pragma unroll
            for (int off = 32; off > 0; off >>= 1) ss1 += __shfl_xor(ss1, off, 64);
            float inv1 = 1.0f / fmaxf(sqrtf(ss1), 1e-12f);
            v1.x *= inv1; v1.y *= inv1;
            *(float2*)(p1 + l * 2) = v1;
        }
    }
}

// ---------------------------------------------------------------------------
extern "C" void kernel_launch(void* const* d_in, const int* in_sizes, int n_in,
                              void* d_out, int out_size, void* d_ws, size_t ws_size,
                              hipStream_t stream) {
    const float* item  = (const float*)d_in[0];
    const float* user  = (const float*)d_in[1];
    const float* W1_0  = (const float*)d_in[2];
    const float* b1_0  = (const float*)d_in[3];
    const float* W2_0  = (const float*)d_in[4];
    const float* b2_0  = (const float*)d_in[5];
    const float* W1_1  = (const float*)d_in[6];
    const float* b1_1  = (const float*)d_in[7];
    const float* W2_1  = (const float*)d_in[8];
    const float* b2_1  = (const float*)d_in[9];
    const float* evals = (const float*)d_in[10];
    const int*   erows = (const int*)d_in[11];
    const int*   ecols = (const int*)d_in[12];
    float* out = (float*)d_out;

    // workspace layout (all 16B-aligned)
    int*   counts  = (int*)d_ws;                          // 50000
    int*   offsets = counts + N_NODES;                    // 50001
    int*   cursors = offsets + (N_NODES + 1);             // ends 150001 ints
    float* svals   = (float*)((int*)d_ws + 150004);       // byte 600016
    int*   scols   = (int*)(svals + N_EDGES);
    unsigned short* wb1_0 = (unsigned short*)(scols + N_EDGES);
    unsigned short* wb2_0 = wb1_0 + (size_t)D0 * D1;
    unsigned short* wb1_1 = wb2_0 + (size_t)D0 * D1;
    unsigned short* wb2_1 = wb1_1 + (size_t)D1 * D2;
    unsigned short* ego0b = wb2_1 + (size_t)D1 * D2;      // byte 5122000, 76.8 MB
    unsigned short* ego1b = ego0b + (size_t)N_NODES * D0; // 12.8 MB

    const size_t need = 5122000 + (size_t)N_NODES * D0 * 2 + (size_t)N_NODES * D1 * 2;
    const bool big = ws_size >= need;   // bf16 gather mirrors fit in workspace?

    // ego0 -> d_out cols [0,768) (+ bf16 mirror) ; zeroes counts
    copy_ego0<<<(N_NODES * (D0 / 4) + 255) / 256, 256, 0, stream>>>(
        item, user, out, big ? ego0b : nullptr, counts);

    // histogram + all weight preps in one dispatch
    aux_kernel<<<2104, 256, 0, stream>>>(erows, counts, W1_0, W2_0, W1_1, W2_1,
                                         wb1_0, wb2_0, wb1_1, wb2_1);
    scan_kernel<<<1, SCAN_THREADS, 0, stream>>>(counts, offsets, cursors);
    fill_kernel<<<(N_EDGES + 255) / 256, 256, 0, stream>>>(evals, erows, ecols,
                                                           cursors, svals, scols);

    if (big) {
        // layer 0 -> ego1 fp32 into d_out cols [768,896) + bf16 mirror
        fused_layer_mfma<D0, D1, 512, true, false><<<N_NODES / 16, 512, 0, stream>>>(
            offsets, svals, scols, out, OSTRIDE, ego0b,
            wb1_0, wb2_0, b1_0, b2_0, out + D0, OSTRIDE, ego1b, nullptr);
        // layer 1 -> normalized ego2 into d_out cols [896,960); also normalizes ego1
        fused_layer_mfma<D1, D2, 256, true, true><<<N_NODES / 16, 256, 0, stream>>>(
            offsets, svals, scols, out + D0, OSTRIDE, ego1b,
            wb1_1, wb2_1, b1_1, b2_1, out + D0 + D1, OSTRIDE, nullptr, out + D0);
    } else {
        fused_layer_mfma<D0, D1, 512, false, false><<<N_NODES / 16, 512, 0, stream>>>(
            offsets, svals, scols, out, OSTRIDE, nullptr,
            wb1_0, wb2_0, b1_0, b2_0, out + D0, OSTRIDE, nullptr, nullptr);
        fused_layer_mfma<D1, D2, 256, false, true><<<N_NODES / 16, 256, 0, stream>>>(
            offsets, svals, scols, out + D0, OSTRIDE, nullptr,
            wb1_1, wb2_1, b1_1, b2_1, out + D0 + D1, OSTRIDE, nullptr, out + D0);
    }
}